// Round 1
// baseline (171.670 us; speedup 1.0000x reference)
//
#include <hip/hip_runtime.h>
#include <math.h>

// HorizonReward: 60-step unscented-transform cartpole rollout with RBF policy.
// Single wave (64 lanes), everything in registers/LDS. Double precision
// internally (chaotic amplification ~1e5 makes f32 drift ~1%; threshold is 2%).

__global__ __launch_bounds__(64) void horizon_kernel(const float* __restrict__ p,
                                                     float* __restrict__ out) {
    const int l = threadIdx.x;

    const double DT   = 0.05;
    const double PML  = 0.05, GRAV = 9.8, LENC = 0.5, MP = 0.1, MT = 1.1;
    const double W0 = 0.2, WI = 0.1;                 // UT weights, kappa=1, n=4
    const double S5 = 2.2360679774997896;            // sqrt(n+kappa) = sqrt(5)
    // process-noise offsets contribute 0.2*5*(PROC_NOISE*DT+JITTER) to the
    // covariance diagonal (exact cancellation of cross terms); gen_sigma then
    // adds JITTER before the cholesky.
    const double DIAG_ADD = 5.0 * 0.2 * (0.01 * 0.05 + 1e-6) + 1e-6;

    // ---- per-lane RBF parameters (zeroed for lanes >= 50 -> contribute 0)
    double w = 0.0, mu0 = 0.0, mu1 = 0.0, mu2 = 0.0, mu3 = 0.0;
    double s0=0,s1=0,s2=0,s3=0,s4=0,s5v=0,s6=0,s7=0,s8=0,s9=0;
    if (l < 50) {
        w   = (double)p[l];
        mu0 = (double)p[ 50 + l];
        mu1 = (double)p[100 + l];
        mu2 = (double)p[150 + l];
        mu3 = (double)p[200 + l];
        const float* q = p + 250 + 10 * l;
        s0 = (double)q[0]; s1 = (double)q[1]; s2 = (double)q[2]; s3 = (double)q[3];
        s4 = (double)q[4]; s5v = (double)q[5]; s6 = (double)q[6]; s7 = (double)q[7];
        s8 = (double)q[8]; s9 = (double)q[9];
    }

    __shared__ double st[4][9];   // current sigma points (rows = state dims)
    __shared__ double nm[4][9];   // next means after dynamics step

    if (l == 0) {
        const double r0 = S5 * sqrt(1e-6);   // chol of (0 + JITTER*I), scaled
        const double x0[4] = {0.0, 0.0, 0.1, 0.0};
        #pragma unroll
        for (int k = 0; k < 4; ++k) {
            st[k][0] = x0[k];
            #pragma unroll
            for (int j = 0; j < 4; ++j) {
                st[k][1 + j] = x0[k] + ((k == j) ? r0 : 0.0);
                st[k][5 + j] = x0[k] - ((k == j) ? r0 : 0.0);
            }
        }
    }
    __syncthreads();

    double acc = 0.0;

    #pragma unroll 1
    for (int t = 0; t < 60; ++t) {
        // ---- mean of current sigma points (redundant, LDS broadcast reads)
        double m0, m1, m2, m3;
        {
            double a0 = W0 * st[0][0], a1 = W0 * st[1][0];
            double a2 = W0 * st[2][0], a3 = W0 * st[3][0];
            #pragma unroll
            for (int i = 1; i < 9; ++i) {
                a0 += WI * st[0][i]; a1 += WI * st[1][i];
                a2 += WI * st[2][i]; a3 += WI * st[3][i];
            }
            m0 = a0; m1 = a1; m2 = a2; m3 = a3;
        }

        // ---- RBF policy: one RBF per lane, butterfly reduce over 64 lanes
        // Ld[j] = sum_k L[k][j] * d[k]  (lower-tri L, transposed application)
        double d0 = m0 - mu0, d1 = m1 - mu1, d2 = m2 - mu2, d3 = m3 - mu3;
        double t0 = s0*d0 + s4*d1 + s5v*d2 + s7*d3;
        double t1 = s1*d1 + s6*d2 + s8*d3;
        double t2 = s2*d2 + s9*d3;
        double t3 = s3*d3;
        double val = w * exp(-(t0*t0 + t1*t1 + t2*t2 + t3*t3));
        #pragma unroll
        for (int off = 32; off > 0; off >>= 1) val += __shfl_xor(val, off);
        double u = fmin(10.0, fmax(-10.0, val));

        // ---- dynamics: lane i < 9 advances sigma point i
        if (l < 9) {
            double pos = st[0][l], vel = st[1][l], th = st[2][l], thd = st[3][l];
            double sn, cs;
            sincos(th, &sn, &cs);
            double temp  = (u + PML * thd * thd * sn) / MT;
            double thacc = (GRAV * sn - cs * temp) /
                           (LENC * (4.0 / 3.0 - MP * cs * cs / MT));
            double xacc  = temp - PML * thacc * cs / MT;
            nm[0][l] = pos + DT * vel;
            nm[1][l] = vel + DT * xacc;
            nm[2][l] = th  + DT * thd;
            nm[3][l] = thd + DT * thacc;
        }
        __syncthreads();

        // ---- redundant on all lanes: next mean, covariance, cholesky, reward
        double nv[4][9];
        #pragma unroll
        for (int k = 0; k < 4; ++k)
            #pragma unroll
            for (int i = 0; i < 9; ++i) nv[k][i] = nm[k][i];

        double mm[4];
        #pragma unroll
        for (int k = 0; k < 4; ++k) {
            double a = W0 * nv[k][0];
            #pragma unroll
            for (int i = 1; i < 9; ++i) a += WI * nv[k][i];
            mm[k] = a;
        }
        #pragma unroll
        for (int k = 0; k < 4; ++k)
            #pragma unroll
            for (int i = 0; i < 9; ++i) nv[k][i] -= mm[k];

        double A[4][4];
        #pragma unroll
        for (int a = 0; a < 4; ++a)
            #pragma unroll
            for (int b = 0; b < 4; ++b)
                if (b <= a) {
                    double sacc = W0 * nv[a][0] * nv[b][0];
                    #pragma unroll
                    for (int i = 1; i < 9; ++i) sacc += WI * nv[a][i] * nv[b][i];
                    A[a][b] = sacc;
                }
        A[0][0] += DIAG_ADD; A[1][1] += DIAG_ADD;
        A[2][2] += DIAG_ADD; A[3][3] += DIAG_ADD;

        // 4x4 lower cholesky
        double L00 = sqrt(A[0][0]);
        double L10 = A[1][0] / L00, L20 = A[2][0] / L00, L30 = A[3][0] / L00;
        double L11 = sqrt(A[1][1] - L10*L10);
        double L21 = (A[2][1] - L20*L10) / L11;
        double L31 = (A[3][1] - L30*L10) / L11;
        double L22 = sqrt(A[2][2] - L20*L20 - L21*L21);
        double L32 = (A[3][2] - L30*L20 - L31*L21) / L22;
        double L33 = sqrt(A[3][3] - L30*L30 - L31*L31 - L32*L32);

        double c00 = S5*L00, c10 = S5*L10, c20 = S5*L20, c30 = S5*L30;
        double c11 = S5*L11, c21 = S5*L21, c31 = S5*L31;
        double c22 = S5*L22, c32 = S5*L32, c33 = S5*L33;

        // regenerated sigma points: col0 = mm, cols 1..4 = mm + chol cols,
        // cols 5..8 = mm - chol cols (strict upper entries are exact zeros)
        double ns[4][9];
        ns[0][0]=mm[0];     ns[1][0]=mm[1];     ns[2][0]=mm[2];     ns[3][0]=mm[3];
        ns[0][1]=mm[0]+c00; ns[1][1]=mm[1]+c10; ns[2][1]=mm[2]+c20; ns[3][1]=mm[3]+c30;
        ns[0][2]=mm[0];     ns[1][2]=mm[1]+c11; ns[2][2]=mm[2]+c21; ns[3][2]=mm[3]+c31;
        ns[0][3]=mm[0];     ns[1][3]=mm[1];     ns[2][3]=mm[2]+c22; ns[3][3]=mm[3]+c32;
        ns[0][4]=mm[0];     ns[1][4]=mm[1];     ns[2][4]=mm[2];     ns[3][4]=mm[3]+c33;
        ns[0][5]=mm[0]-c00; ns[1][5]=mm[1]-c10; ns[2][5]=mm[2]-c20; ns[3][5]=mm[3]-c30;
        ns[0][6]=mm[0];     ns[1][6]=mm[1]-c11; ns[2][6]=mm[2]-c21; ns[3][6]=mm[3]-c31;
        ns[0][7]=mm[0];     ns[1][7]=mm[1];     ns[2][7]=mm[2]-c22; ns[3][7]=mm[3]-c32;
        ns[0][8]=mm[0];     ns[1][8]=mm[1];     ns[2][8]=mm[2];     ns[3][8]=mm[3]-c33;

        double rw = W0 * (ns[0][0]*ns[0][0] + ns[1][0]*ns[1][0]
                          + 10.0*ns[2][0]*ns[2][0] + ns[3][0]*ns[3][0]);
        #pragma unroll
        for (int i = 1; i < 9; ++i)
            rw += WI * (ns[0][i]*ns[0][i] + ns[1][i]*ns[1][i]
                        + 10.0*ns[2][i]*ns[2][i] + ns[3][i]*ns[3][i]);
        acc -= rw;

        // write regenerated sigma points for the next iteration
        if (l == 0) {
            #pragma unroll
            for (int k = 0; k < 4; ++k)
                #pragma unroll
                for (int i = 0; i < 9; ++i) st[k][i] = ns[k][i];
        }
        __syncthreads();
    }

    if (l == 0) out[0] = (float)acc;
}

extern "C" void kernel_launch(void* const* d_in, const int* in_sizes, int n_in,
                              void* d_out, int out_size, void* d_ws, size_t ws_size,
                              hipStream_t stream) {
    (void)in_sizes; (void)n_in; (void)out_size; (void)d_ws; (void)ws_size;
    const float* p = (const float*)d_in[0];
    float* out = (float*)d_out;
    hipLaunchKernelGGL(horizon_kernel, dim3(1), dim3(64), 0, stream, p, out);
}

// Round 2
// 125.084 us; speedup vs baseline: 1.3724x; 1.3724x over previous
//
#include <hip/hip_runtime.h>
#include <math.h>

// HorizonReward: 60-step UT cartpole rollout, single wave, zero LDS/barriers.
// Mean trajectory in f64 (chaos amplifies ~7e5; per-step error must be <2e-9);
// covariance / cholesky / offsets in f32 (second-order effect on the mean:
// +/- sigma pairs share the same column, so offset errors cancel to 1st order).

__device__ __forceinline__ double bsum64(double v) {
    #pragma unroll
    for (int off = 32; off > 0; off >>= 1) v += __shfl_xor(v, off);
    return v;
}
__device__ __forceinline__ float bsum64f(float v) {
    #pragma unroll
    for (int off = 32; off > 0; off >>= 1) v += __shfl_xor(v, off);
    return v;
}

// exp(-q), q >= 0. Range-reduce by ln2, Taylor deg 9. rel err ~1e-11.
__device__ __forceinline__ double exp_neg(double q) {
    double x = -fmin(q, 700.0);
    double kd = rint(x * 1.4426950408889634);
    double r = fma(-kd, 6.93147180369123816490e-01, x);   // ln2_hi (fdlibm)
    r = fma(-kd, 1.90821492927058770002e-10, r);          // ln2_lo
    double p = 2.755731922398589e-06;                     // 1/9!
    p = fma(p, r, 2.4801587301587302e-05);                // 1/8!
    p = fma(p, r, 1.984126984126984e-04);                 // 1/7!
    p = fma(p, r, 1.3888888888888889e-03);                // 1/6!
    p = fma(p, r, 8.333333333333333e-03);                 // 1/5!
    p = fma(p, r, 4.1666666666666664e-02);                // 1/4!
    p = fma(p, r, 1.6666666666666666e-01);                // 1/3!
    p = fma(p, r, 0.5);
    p = fma(p, r, 1.0);
    p = fma(p, r, 1.0);
    int k = (int)kd;                                      // k in [-1010, 0]
    double sc = __longlong_as_double((long long)(1023 + k) << 52);
    return p * sc;
}

// sincos via pi range reduction + Taylor (sin deg 15, cos deg 16). err ~1e-11.
__device__ __forceinline__ void fast_sincos(double th, double& s, double& c) {
    double kd = rint(th * 0.3183098861837907);            // th/pi
    double r = fma(-kd, 3.141592653589793, th);
    r = fma(-kd, 1.2246467991473532e-16, r);              // pi tail
    double r2 = r * r;
    double ps = -7.647163731819816e-13;                   // -1/15!
    ps = fma(ps, r2, 1.605904383682161e-10);              //  1/13!
    ps = fma(ps, r2, -2.505210838544172e-08);             // -1/11!
    ps = fma(ps, r2, 2.755731922398589e-06);              //  1/9!
    ps = fma(ps, r2, -1.984126984126984e-04);             // -1/7!
    ps = fma(ps, r2, 8.333333333333333e-03);              //  1/5!
    ps = fma(ps, r2, -1.6666666666666666e-01);            // -1/3!
    double sr = fma(r2 * r, ps, r);
    double pc = 4.779477332387385e-14;                    //  1/16!
    pc = fma(pc, r2, -1.1470745597729725e-11);            // -1/14!
    pc = fma(pc, r2, 2.08767569878681e-09);               //  1/12!
    pc = fma(pc, r2, -2.755731922398589e-07);             // -1/10!
    pc = fma(pc, r2, 2.48015873015873e-05);               //  1/8!
    pc = fma(pc, r2, -1.3888888888888889e-03);            // -1/6!
    pc = fma(pc, r2, 4.1666666666666664e-02);             //  1/4!
    pc = fma(pc, r2, -0.5);
    double cr = fma(r2, pc, 1.0);
    int k = (int)kd;
    double sgn = (k & 1) ? -1.0 : 1.0;
    s = sr * sgn;
    c = cr * sgn;
}

__global__ __launch_bounds__(64) void horizon_kernel(const float* __restrict__ p,
                                                     float* __restrict__ out) {
    const int l = threadIdx.x;

    const double S5 = 2.2360679774997896;                 // sqrt(5)
    const float  S5F = (float)S5;
    const double INV_MT = 0.9090909090909091;             // 1/1.1
    // proc-noise diag (exact: 2*WI*5*(PN*DT+J) = PN*DT+J) + gen_sigma jitter
    const float DIAG_ADD = (float)(0.01 * 0.05 + 1e-6 + 1e-6);

    // ---- per-lane RBF parameters (zero for lanes >= 50 -> contribute 0)
    double w = 0.0, mu0 = 0.0, mu1 = 0.0, mu2 = 0.0, mu3 = 0.0;
    double s0=0,s1=0,s2=0,s3=0,s4=0,s5v=0,s6=0,s7=0,s8=0,s9=0;
    if (l < 50) {
        w   = (double)p[l];
        mu0 = (double)p[ 50 + l];
        mu1 = (double)p[100 + l];
        mu2 = (double)p[150 + l];
        mu3 = (double)p[200 + l];
        const float* q = p + 250 + 10 * l;
        s0 = (double)q[0]; s1 = (double)q[1]; s2 = (double)q[2]; s3 = (double)q[3];
        s4 = (double)q[4]; s5v = (double)q[5]; s6 = (double)q[6]; s7 = (double)q[7];
        s8 = (double)q[8]; s9 = (double)q[9];
    }

    // UT lane weight and sigma-offset selector (lanes 1..4: +col, 5..8: -col)
    const double wl   = (l == 0) ? 0.2 : ((l < 9) ? 0.1 : 0.0);
    const double osgn = (l >= 1 && l <= 4) ? 1.0 : ((l >= 5 && l <= 8) ? -1.0 : 0.0);
    const int    ocol = ((l >= 5 ? l - 5 : l - 1) & 3);   // garbage ok when osgn=0

    // carried state: mean (f64) + sqrt5-scaled chol columns (f32, lower tri)
    double mm0 = 0.0, mm1 = 0.0, mm2 = 0.1, mm3 = 0.0;
    const float CI = (float)(S5 * 1.0e-3);                // sqrt5*chol(JITTER*I)
    float c00=CI, c10=0, c20=0, c30=0, c11=CI, c21=0, c31=0, c22=CI, c32=0, c33=CI;

    double acc = 0.0;

    #pragma unroll 1
    for (int t = 0; t < 60; ++t) {
        // ---- policy at the mean (mean of sigma points == mm exactly)
        double d0 = mm0 - mu0, d1 = mm1 - mu1, d2 = mm2 - mu2, d3 = mm3 - mu3;
        double t0 = fma(s0, d0, fma(s4, d1, fma(s5v, d2, s7 * d3)));
        double t1 = fma(s1, d1, fma(s6, d2, s8 * d3));
        double t2 = fma(s2, d2, s9 * d3);
        double t3 = s3 * d3;
        double qn = fma(t0, t0, fma(t1, t1, fma(t2, t2, t3 * t3)));
        double val = bsum64(w * exp_neg(qn));
        double u = fmin(10.0, fmax(-10.0, val));

        // ---- this lane's sigma point: mm + osgn * column(ocol)
        float o0 = (ocol == 0) ? c00 : 0.0f;
        float o1 = (ocol == 0) ? c10 : ((ocol == 1) ? c11 : 0.0f);
        float o2 = (ocol == 0) ? c20 : ((ocol == 1) ? c21 : ((ocol == 2) ? c22 : 0.0f));
        float o3 = (ocol == 0) ? c30 : ((ocol == 1) ? c31 : ((ocol == 2) ? c32 : c33));
        double x0 = fma(osgn, (double)o0, mm0);
        double x1 = fma(osgn, (double)o1, mm1);
        double x2 = fma(osgn, (double)o2, mm2);
        double x3 = fma(osgn, (double)o3, mm3);

        // ---- cartpole dynamics (f64; divides -> reciprocals)
        double sn, cs;
        fast_sincos(x2, sn, cs);
        double temp = (u + 0.05 * (x3 * x3) * sn) * INV_MT;
        double csc = cs * cs;
        double den = 0.5 * (4.0 / 3.0 - csc * (0.1 * INV_MT));
        double r = (double)__builtin_amdgcn_rcpf((float)den);
        r = r * fma(-den, r, 2.0);                        // Newton x2 -> ~1e-16
        r = r * fma(-den, r, 2.0);
        double thacc = fma(9.8, sn, -(cs * temp)) * r;
        double xacc = fma(-0.05 * INV_MT, thacc * cs, temp);
        double n0 = fma(0.05, x1, x0);
        double n1 = fma(0.05, xacc, x1);
        double n2 = fma(0.05, x3, x2);
        double n3 = fma(0.05, thacc, x3);

        // ---- UT mean (f64 butterflies; lanes >= 9 carry weight 0)
        double m0 = bsum64(wl * n0);
        double m1 = bsum64(wl * n1);
        double m2 = bsum64(wl * n2);
        double m3 = bsum64(wl * n3);

        // ---- UT covariance in f32 (mean-subtracted -> no cancellation)
        float v0 = (float)(n0 - m0), v1 = (float)(n1 - m1);
        float v2 = (float)(n2 - m2), v3 = (float)(n3 - m3);
        float fw = (float)wl;
        float a00 = bsum64f(fw * v0 * v0) + DIAG_ADD;
        float a10 = bsum64f(fw * v1 * v0);
        float a20 = bsum64f(fw * v2 * v0);
        float a30 = bsum64f(fw * v3 * v0);
        float a11 = bsum64f(fw * v1 * v1) + DIAG_ADD;
        float a21 = bsum64f(fw * v2 * v1);
        float a31 = bsum64f(fw * v3 * v1);
        float a22 = bsum64f(fw * v2 * v2) + DIAG_ADD;
        float a32 = bsum64f(fw * v3 * v2);
        float a33 = bsum64f(fw * v3 * v3) + DIAG_ADD;

        // ---- reward, algebraic: m'Qm + tr(Q*(covc+J*I))   (Q=diag(1,1,10,1))
        double rwm = fma(m0, m0, fma(m1, m1, fma(10.0 * m2, m2, m3 * m3)));
        float  rwa = a00 + a11 + 10.0f * a22 + a33;
        acc -= rwm + (double)rwa;

        // ---- 4x4 cholesky in f32 via v_rsq_f32 (feeds next-iter offsets only)
        float i0 = __builtin_amdgcn_rsqf(a00);
        float L00 = a00 * i0;
        float L10 = a10 * i0, L20 = a20 * i0, L30 = a30 * i0;
        float b11 = fmaf(-L10, L10, a11);
        float i1 = __builtin_amdgcn_rsqf(b11);
        float L11 = b11 * i1;
        float L21 = fmaf(-L20, L10, a21) * i1;
        float L31 = fmaf(-L30, L10, a31) * i1;
        float b22 = fmaf(-L21, L21, fmaf(-L20, L20, a22));
        float i2 = __builtin_amdgcn_rsqf(b22);
        float L22 = b22 * i2;
        float L32 = fmaf(-L31, L21, fmaf(-L30, L20, a32)) * i2;
        float b33 = fmaf(-L32, L32, fmaf(-L31, L31, fmaf(-L30, L30, a33)));
        float L33 = b33 * __builtin_amdgcn_rsqf(b33);

        c00 = S5F * L00; c10 = S5F * L10; c20 = S5F * L20; c30 = S5F * L30;
        c11 = S5F * L11; c21 = S5F * L21; c31 = S5F * L31;
        c22 = S5F * L22; c32 = S5F * L32; c33 = S5F * L33;

        mm0 = m0; mm1 = m1; mm2 = m2; mm3 = m3;
    }

    if (l == 0) out[0] = (float)acc;
}

extern "C" void kernel_launch(void* const* d_in, const int* in_sizes, int n_in,
                              void* d_out, int out_size, void* d_ws, size_t ws_size,
                              hipStream_t stream) {
    (void)in_sizes; (void)n_in; (void)out_size; (void)d_ws; (void)ws_size;
    const float* p = (const float*)d_in[0];
    float* out = (float*)d_out;
    hipLaunchKernelGGL(horizon_kernel, dim3(1), dim3(64), 0, stream, p, out);
}

// Round 3
// 87.303 us; speedup vs baseline: 1.9664x; 1.4328x over previous
//
#include <hip/hip_runtime.h>
#include <math.h>

// HorizonReward: 60-step UT cartpole rollout, single wave.
// All cross-lane traffic via DPP (VALU pipe, ~5 cyc) + v_readlane broadcast —
// zero LDS, zero ds_bpermute (each of those costs ~115 cyc single-wave).
// Mean trajectory f64 (chaos amplifies ~7e5); covariance/cholesky f32.

// DPP ctrl codes: quad_perm[1,0,3,2]=0xB1, quad_perm[2,3,0,1]=0x4E,
// row_ror:4=0x124, row_ror:8=0x128. Sequence of the four = every lane in a
// 16-lane row ends up with the row's sum (cyclic pair sums cover all quads).

template <int CTRL>
__device__ __forceinline__ float dpp_add_f(float v) {
    int s = __builtin_amdgcn_update_dpp(0, __float_as_int(v), CTRL, 0xF, 0xF, true);
    return v + __int_as_float(s);
}
template <int CTRL>
__device__ __forceinline__ double dpp_add_d(double v) {
    long long b = __double_as_longlong(v);
    int lo = (int)b, hi = (int)(b >> 32);
    int slo = __builtin_amdgcn_update_dpp(0, lo, CTRL, 0xF, 0xF, true);
    int shi = __builtin_amdgcn_update_dpp(0, hi, CTRL, 0xF, 0xF, true);
    long long sb = ((long long)(unsigned)shi << 32) | (unsigned)slo;
    return v + __longlong_as_double(sb);
}
__device__ __forceinline__ double row_sum_d(double v) {
    v = dpp_add_d<0xB1>(v); v = dpp_add_d<0x4E>(v);
    v = dpp_add_d<0x124>(v); v = dpp_add_d<0x128>(v);
    return v;   // row sum, uniform within each 16-lane row
}
__device__ __forceinline__ float row_sum_f(float v) {
    v = dpp_add_f<0xB1>(v); v = dpp_add_f<0x4E>(v);
    v = dpp_add_f<0x124>(v); v = dpp_add_f<0x128>(v);
    return v;
}
__device__ __forceinline__ double lane_d(double v, int lane) {
    long long b = __double_as_longlong(v);
    int lo = __builtin_amdgcn_readlane((int)b, lane);
    int hi = __builtin_amdgcn_readlane((int)(b >> 32), lane);
    return __longlong_as_double(((long long)(unsigned)hi << 32) | (unsigned)lo);
}
__device__ __forceinline__ float lane_f(float v, int lane) {
    return __int_as_float(__builtin_amdgcn_readlane(__float_as_int(v), lane));
}
// sum over lanes 0..8 (others must be zero), broadcast to all lanes
__device__ __forceinline__ double row0_sum_d(double v) { return lane_d(row_sum_d(v), 0); }
__device__ __forceinline__ float  row0_sum_f(float v)  { return lane_f(row_sum_f(v), 0); }
// full 64-lane sum, broadcast to all lanes
__device__ __forceinline__ double wave_sum_d(double v) {
    v = row_sum_d(v);
    return (lane_d(v, 0) + lane_d(v, 16)) + (lane_d(v, 32) + lane_d(v, 48));
}

// exp(-q), q >= 0. ln2 range reduction + deg-9 Taylor, Estrin even/odd split.
__device__ __forceinline__ double exp_neg(double q) {
    double x = -fmin(q, 700.0);
    double kd = rint(x * 1.4426950408889634);
    double r = fma(-kd, 6.93147180369123816490e-01, x);
    r = fma(-kd, 1.90821492927058770002e-10, r);
    double r2 = r * r;
    double e = 2.4801587301587302e-05;                 // 1/8!
    e = fma(e, r2, 1.3888888888888889e-03);            // 1/6!
    e = fma(e, r2, 4.1666666666666664e-02);            // 1/4!
    e = fma(e, r2, 0.5);                               // 1/2!
    e = fma(e, r2, 1.0);                               // 1
    double o = 2.755731922398589e-06;                  // 1/9!
    o = fma(o, r2, 1.984126984126984e-04);             // 1/7!
    o = fma(o, r2, 8.333333333333333e-03);             // 1/5!
    o = fma(o, r2, 1.6666666666666666e-01);            // 1/3!
    o = fma(o, r2, 1.0);                               // 1/1!
    double p = fma(r, o, e);
    int k = (int)kd;
    double sc = __longlong_as_double((long long)(1023 + k) << 52);
    return p * sc;
}

// sincos: pi range reduction + Taylor (sin deg 15, cos deg 16), Estrin.
__device__ __forceinline__ void fast_sincos(double th, double& s, double& c) {
    double kd = rint(th * 0.3183098861837907);
    double r = fma(-kd, 3.141592653589793, th);
    r = fma(-kd, 1.2246467991473532e-16, r);
    double x = r * r, x2 = x * x, x4 = x2 * x2;
    // sin = r * S(x), S = s0..s7
    double sp0 = fma(-1.6666666666666666e-01, x, 1.0);
    double sp1 = fma(-1.984126984126984e-04, x, 8.333333333333333e-03);
    double sp2 = fma(-2.505210838544172e-08, x, 2.755731922398589e-06);
    double sp3 = fma(-7.647163731819816e-13, x, 1.605904383682161e-10);
    double sq0 = fma(sp1, x2, sp0);
    double sq1 = fma(sp3, x2, sp2);
    double S = fma(sq1, x4, sq0);
    double sr = r * S;
    // cos = 1 + x * H(x), H = c1..c8
    double cp0 = fma(4.1666666666666664e-02, x, -0.5);
    double cp1 = fma(2.48015873015873e-05, x, -1.3888888888888889e-03);
    double cp2 = fma(2.08767569878681e-09, x, -2.755731922398589e-07);
    double cp3 = fma(4.779477332387385e-14, x, -1.1470745597729725e-11);
    double cq0 = fma(cp1, x2, cp0);
    double cq1 = fma(cp3, x2, cp2);
    double H = fma(cq1, x4, cq0);
    double cr = fma(x, H, 1.0);
    int k = (int)kd;
    double sgn = (k & 1) ? -1.0 : 1.0;
    s = sr * sgn;
    c = cr * sgn;
}

__global__ __launch_bounds__(64) void horizon_kernel(const float* __restrict__ p,
                                                     float* __restrict__ out) {
    const int l = threadIdx.x;

    const double S5 = 2.2360679774997896;              // sqrt(5)
    const float  S5F = (float)S5;
    const double INV_MT = 0.9090909090909091;          // 1/1.1
    const float DIAG_ADD = (float)(0.01 * 0.05 + 1e-6 + 1e-6);

    // per-lane RBF parameters (zero for lanes >= 50 -> contribute 0)
    double w = 0.0, mu0 = 0.0, mu1 = 0.0, mu2 = 0.0, mu3 = 0.0;
    double s0=0,s1=0,s2=0,s3=0,s4=0,s5v=0,s6=0,s7=0,s8=0,s9=0;
    if (l < 50) {
        w   = (double)p[l];
        mu0 = (double)p[ 50 + l];
        mu1 = (double)p[100 + l];
        mu2 = (double)p[150 + l];
        mu3 = (double)p[200 + l];
        const float* q = p + 250 + 10 * l;
        s0 = (double)q[0]; s1 = (double)q[1]; s2 = (double)q[2]; s3 = (double)q[3];
        s4 = (double)q[4]; s5v = (double)q[5]; s6 = (double)q[6]; s7 = (double)q[7];
        s8 = (double)q[8]; s9 = (double)q[9];
    }

    const double wl   = (l == 0) ? 0.2 : ((l < 9) ? 0.1 : 0.0);
    const double osgn = (l >= 1 && l <= 4) ? 1.0 : ((l >= 5 && l <= 8) ? -1.0 : 0.0);
    const int    ocol = ((l >= 5 ? l - 5 : l - 1) & 3);

    double mm0 = 0.0, mm1 = 0.0, mm2 = 0.1, mm3 = 0.0;
    const float CI = (float)(S5 * 1.0e-3);
    float c00=CI, c10=0, c20=0, c30=0, c11=CI, c21=0, c31=0, c22=CI, c32=0, c33=CI;

    double acc = 0.0;

    #pragma unroll 2
    for (int t = 0; t < 60; ++t) {
        // ---- policy at the mean (mean of sigma points == mm exactly)
        double d0 = mm0 - mu0, d1 = mm1 - mu1, d2 = mm2 - mu2, d3 = mm3 - mu3;
        double t0 = fma(s0, d0, fma(s4, d1, fma(s5v, d2, s7 * d3)));
        double t1 = fma(s1, d1, fma(s6, d2, s8 * d3));
        double t2 = fma(s2, d2, s9 * d3);
        double t3 = s3 * d3;
        double qn = fma(t0, t0, fma(t1, t1, fma(t2, t2, t3 * t3)));
        double val = wave_sum_d(w * exp_neg(qn));
        double u = fmin(10.0, fmax(-10.0, val));

        // ---- this lane's sigma point: mm + osgn * column(ocol)
        float o0 = (ocol == 0) ? c00 : 0.0f;
        float o1 = (ocol == 0) ? c10 : ((ocol == 1) ? c11 : 0.0f);
        float o2 = (ocol == 0) ? c20 : ((ocol == 1) ? c21 : ((ocol == 2) ? c22 : 0.0f));
        float o3 = (ocol == 0) ? c30 : ((ocol == 1) ? c31 : ((ocol == 2) ? c32 : c33));
        double x0 = fma(osgn, (double)o0, mm0);
        double x1 = fma(osgn, (double)o1, mm1);
        double x2 = fma(osgn, (double)o2, mm2);
        double x3 = fma(osgn, (double)o3, mm3);

        // ---- cartpole dynamics (f64)
        double sn, cs;
        fast_sincos(x2, sn, cs);
        double temp = (u + 0.05 * (x3 * x3) * sn) * INV_MT;
        double csc = cs * cs;
        double den = 0.5 * (4.0 / 3.0 - csc * (0.1 * INV_MT));
        double r = (double)__builtin_amdgcn_rcpf((float)den);
        r = r * fma(-den, r, 2.0);
        r = r * fma(-den, r, 2.0);
        double thacc = fma(9.8, sn, -(cs * temp)) * r;
        double xacc = fma(-0.05 * INV_MT, thacc * cs, temp);
        double n0 = fma(0.05, x1, x0);
        double n1 = fma(0.05, xacc, x1);
        double n2 = fma(0.05, x3, x2);
        double n3 = fma(0.05, thacc, x3);

        // ---- UT mean: contributions live in lanes 0..8 only (row 0)
        double m0 = row0_sum_d(wl * n0);
        double m1 = row0_sum_d(wl * n1);
        double m2 = row0_sum_d(wl * n2);
        double m3 = row0_sum_d(wl * n3);

        // ---- UT covariance in f32 (mean-subtracted -> no cancellation)
        float v0 = (float)(n0 - m0), v1 = (float)(n1 - m1);
        float v2 = (float)(n2 - m2), v3 = (float)(n3 - m3);
        float fw = (float)wl;
        float a00 = row0_sum_f(fw * v0 * v0) + DIAG_ADD;
        float a10 = row0_sum_f(fw * v1 * v0);
        float a20 = row0_sum_f(fw * v2 * v0);
        float a30 = row0_sum_f(fw * v3 * v0);
        float a11 = row0_sum_f(fw * v1 * v1) + DIAG_ADD;
        float a21 = row0_sum_f(fw * v2 * v1);
        float a31 = row0_sum_f(fw * v3 * v1);
        float a22 = row0_sum_f(fw * v2 * v2) + DIAG_ADD;
        float a32 = row0_sum_f(fw * v3 * v2);
        float a33 = row0_sum_f(fw * v3 * v3) + DIAG_ADD;

        // ---- reward, algebraic: m'Qm + tr(Q*covc), Q = diag(1,1,10,1)
        double rwm = fma(m0, m0, fma(m1, m1, fma(10.0 * m2, m2, m3 * m3)));
        float  rwa = a00 + a11 + 10.0f * a22 + a33;
        acc -= rwm + (double)rwa;

        // ---- 4x4 cholesky in f32 (feeds next-iter sigma offsets only)
        float i0 = __builtin_amdgcn_rsqf(a00);
        float L00 = a00 * i0;
        float L10 = a10 * i0, L20 = a20 * i0, L30 = a30 * i0;
        float b11 = fmaf(-L10, L10, a11);
        float i1 = __builtin_amdgcn_rsqf(b11);
        float L11 = b11 * i1;
        float L21 = fmaf(-L20, L10, a21) * i1;
        float L31 = fmaf(-L30, L10, a31) * i1;
        float b22 = fmaf(-L21, L21, fmaf(-L20, L20, a22));
        float i2 = __builtin_amdgcn_rsqf(b22);
        float L22 = b22 * i2;
        float L32 = fmaf(-L31, L21, fmaf(-L30, L20, a32)) * i2;
        float b33 = fmaf(-L32, L32, fmaf(-L31, L31, fmaf(-L30, L30, a33)));
        float L33 = b33 * __builtin_amdgcn_rsqf(b33);

        c00 = S5F * L00; c10 = S5F * L10; c20 = S5F * L20; c30 = S5F * L30;
        c11 = S5F * L11; c21 = S5F * L21; c31 = S5F * L31;
        c22 = S5F * L22; c32 = S5F * L32; c33 = S5F * L33;

        mm0 = m0; mm1 = m1; mm2 = m2; mm3 = m3;
    }

    if (l == 0) out[0] = (float)acc;
}

extern "C" void kernel_launch(void* const* d_in, const int* in_sizes, int n_in,
                              void* d_out, int out_size, void* d_ws, size_t ws_size,
                              hipStream_t stream) {
    (void)in_sizes; (void)n_in; (void)out_size; (void)d_ws; (void)ws_size;
    const float* p = (const float*)d_in[0];
    float* out = (float*)d_out;
    hipLaunchKernelGGL(horizon_kernel, dim3(1), dim3(64), 0, stream, p, out);
}

// Round 4
// 73.292 us; speedup vs baseline: 2.3423x; 1.1912x over previous
//
#include <hip/hip_runtime.h>
#include <math.h>

// HorizonReward: 60-step UT cartpole rollout, single wave, zero LDS.
// f32 compute with hardware transcendentals (v_exp_f32/v_sin_f32/v_cos_f32);
// carried mean + angle range-reduction in f64 (chaos amplifies per-step error
// by ~8e5, so the accumulated state must stay f64; everything else is noise
// at the ~1-absolute level vs threshold 596).
//
// Row replication: sigma-point roles keyed on (lane&15), all inputs are
// lane-uniform, so all 4 DPP rows hold identical data. Mean row-sums are
// therefore wave-uniform with NO readlane broadcast, and the 10 covariance
// entries are computed 3-per-row (12 DPP ops instead of 40).

template <int CTRL>
__device__ __forceinline__ float dpp_add_f(float v) {
    int s = __builtin_amdgcn_update_dpp(0, __float_as_int(v), CTRL, 0xF, 0xF, true);
    return v + __int_as_float(s);
}
// sum within each 16-lane row (quad_perm swaps + row rotates)
__device__ __forceinline__ float row_sum_f(float v) {
    v = dpp_add_f<0xB1>(v);    // quad_perm [1,0,3,2]
    v = dpp_add_f<0x4E>(v);    // quad_perm [2,3,0,1]
    v = dpp_add_f<0x124>(v);   // row_ror:4
    v = dpp_add_f<0x128>(v);   // row_ror:8
    return v;
}
__device__ __forceinline__ float lane_f(float v, int lane) {
    return __int_as_float(__builtin_amdgcn_readlane(__float_as_int(v), lane));
}
// full 64-lane sum: row sums + row_bcast15 + row_bcast31 -> lane 63 has total
__device__ __forceinline__ float wave_sum_f(float v) {
    v = row_sum_f(v);
    v = dpp_add_f<0x142>(v);   // row_bcast15
    v = dpp_add_f<0x143>(v);   // row_bcast31
    return lane_f(v, 63);
}

__global__ __launch_bounds__(64) void horizon_kernel(const float* __restrict__ p,
                                                     float* __restrict__ out) {
    const int l   = threadIdx.x;
    const int l15 = l & 15;
    const int row = l >> 4;

    const float SQL2E = 1.2011224087864498f;   // sqrt(log2(e))

    // per-lane RBF params; s scaled so qn' = qn*log2e -> exp(-qn) = exp2(-qn')
    float w = 0.0f, mu0 = 0.0f, mu1 = 0.0f, mu2 = 0.0f, mu3 = 0.0f;
    float s0=0,s1=0,s2=0,s3=0,s4=0,s5=0,s6=0,s7=0,s8=0,s9=0;
    if (l < 50) {
        w   = p[l];
        mu0 = p[ 50 + l]; mu1 = p[100 + l]; mu2 = p[150 + l]; mu3 = p[200 + l];
        const float* q = p + 250 + 10 * l;
        s0 = q[0]*SQL2E; s1 = q[1]*SQL2E; s2 = q[2]*SQL2E; s3 = q[3]*SQL2E;
        s4 = q[4]*SQL2E; s5 = q[5]*SQL2E; s6 = q[6]*SQL2E; s7 = q[7]*SQL2E;
        s8 = q[8]*SQL2E; s9 = q[9]*SQL2E;
    }

    // sigma-point role from (l&15): replicated across all 4 rows
    const float wlf  = (l15 == 0) ? 0.2f : ((l15 < 9) ? 0.1f : 0.0f);
    const float fw5  = 5.0f * wlf;
    const float osgn = (l15 >= 1 && l15 <= 4) ? 1.0f
                     : ((l15 >= 5 && l15 <= 8) ? -1.0f : 0.0f);
    const int   ocol = ((l15 >= 5 ? l15 - 5 : l15 - 1) & 3);

    // carried state: f64 mean + f32 mirror, policy deltas, sqrt5-scaled chol
    double mm0 = 0.0, mm1 = 0.0, mm2 = 0.1, mm3 = 0.0;
    float mmf0 = 0.0f, mmf1 = 0.0f, mmf2 = 0.1f, mmf3 = 0.0f;
    float d0 = mmf0 - mu0, d1 = mmf1 - mu1, d2 = mmf2 - mu2, d3 = mmf3 - mu3;
    float frmf = (float)(0.1 * 0.15915494309189535);   // fract(theta/2pi)
    const float CI = 2.2360679774997896e-3f;           // sqrt5*chol(JITTER*I)
    float c00=CI, c10=0.f, c20=0.f, c30=0.f;
    float c11=CI, c21=0.f, c31=0.f;
    float c22=CI, c32=0.f;
    float c33=CI;
    double acc = 0.0;

    // DIAG5 = 5*(PROC_NOISE*DT + JITTER + JITTER): proc-noise offsets add
    // exactly (PN*DT+J)*I to covc; gen_sigma adds J; chol(5A)=sqrt5*chol(A).
    const float DIAG5 = 0.00251f;

    #pragma unroll 4
    for (int t = 0; t < 60; ++t) {
        // ---- policy at the mean (d carried from previous iter's mean update)
        float t0v = fmaf(s0, d0, fmaf(s4, d1, fmaf(s5, d2, s7 * d3)));
        float t1v = fmaf(s1, d1, fmaf(s6, d2, s8 * d3));
        float t2v = fmaf(s2, d2, s9 * d3);
        float t3v = s3 * d3;
        float qn = fmaf(t0v, t0v, fmaf(t1v, t1v, fmaf(t2v, t2v, t3v * t3v)));
        float val = wave_sum_f(w * __builtin_amdgcn_exp2f(-qn));
        float u = fminf(10.0f, fmaxf(-10.0f, val));

        // ---- this lane's sigma offset (column ocol of scaled chol, +/-)
        float oo0 = osgn * ((ocol == 0) ? c00 : 0.0f);
        float oo1 = osgn * ((ocol == 0) ? c10 : ((ocol == 1) ? c11 : 0.0f));
        float oo2 = osgn * ((ocol == 0) ? c20 : ((ocol == 1) ? c21 :
                            ((ocol == 2) ? c22 : 0.0f)));
        float oo3 = osgn * ((ocol == 0) ? c30 : ((ocol == 1) ? c31 :
                            ((ocol == 2) ? c32 : c33)));

        float x1 = mmf1 + oo1;
        float x3 = mmf3 + oo3;

        // ---- dynamics (f32, hw transcendentals; angle frac carried in f64)
        float rv = __builtin_amdgcn_fractf(fmaf(oo2, 0.15915494309189535f, frmf));
        float sn = __builtin_amdgcn_sinf(rv);
        float cs = __builtin_amdgcn_cosf(rv);
        float temp  = fmaf(0.05f * (x3 * x3), sn, u) * 0.9090909090909091f;
        float csc   = cs * cs;
        float den   = fmaf(csc, -0.045454545454545456f, 0.6666666666666666f);
        float rden  = __builtin_amdgcn_rcpf(den);
        float thacc = fmaf(9.8f, sn, -(cs * temp)) * rden;
        float xacc  = fmaf(-0.045454545454545456f, thacc * cs, temp);

        // delta = sigma offset + DT*deriv  (small; n = mm + delta exactly)
        float dl0 = fmaf(0.05f, x1,    oo0);
        float dl1 = fmaf(0.05f, xacc,  oo1);
        float dl2 = fmaf(0.05f, x3,    oo2);
        float dl3 = fmaf(0.05f, thacc, oo3);

        // ---- mean increment: row-replicated -> row sums are wave-uniform
        float rd0 = row_sum_f(wlf * dl0);
        float rd1 = row_sum_f(wlf * dl1);
        float rd2 = row_sum_f(wlf * dl2);
        float rd3 = row_sum_f(wlf * dl3);

        mm0 += (double)rd0; mm1 += (double)rd1;
        mm2 += (double)rd2; mm3 += (double)rd3;
        mmf0 = (float)mm0; mmf1 = (float)mm1;
        mmf2 = (float)mm2; mmf3 = (float)mm3;
        d0 = mmf0 - mu0; d1 = mmf1 - mu1; d2 = mmf2 - mu2; d3 = mmf3 - mu3;
        double rev = mm2 * 0.15915494309189535;
        frmf = (float)(rev - floor(rev));

        // ---- covariance*5: deviations v = delta - rd; 3 products per row
        // row0: a00,a10,a20  row1: a30,a11,a21  row2: a31,a22,a32  row3: a33
        float v0 = dl0 - rd0, v1 = dl1 - rd1, v2 = dl2 - rd2, v3 = dl3 - rd3;
        float a1 = (row == 0) ? v0 : v3;
        float b1 = (row <= 1) ? v0 : ((row == 2) ? v1 : v3);
        float a2 = (row <= 1) ? v1 : v2;
        float b2 = (row == 0) ? v0 : ((row == 1) ? v1 : v2);
        float a3 = (row <= 1) ? v2 : v3;
        float P1 = row_sum_f(fw5 * a1 * b1);
        float P2 = row_sum_f(fw5 * a2 * b2);
        float P3 = row_sum_f(fw5 * a3 * b2);

        float A00 = lane_f(P1,  0) + DIAG5;
        float A30 = lane_f(P1, 16);
        float A31 = lane_f(P1, 32);
        float A33 = lane_f(P1, 48) + DIAG5;
        float A10 = lane_f(P2,  0);
        float A11 = lane_f(P2, 16) + DIAG5;
        float A22 = lane_f(P2, 32) + DIAG5;
        float A20 = lane_f(P3,  0);
        float A21 = lane_f(P3, 16);
        float A32 = lane_f(P3, 32);

        // ---- reward: m'Qm + tr(Q*(covc+J*I)) = rwm + rwa/5,  Q=diag(1,1,10,1)
        float rwm = fmaf(mmf0, mmf0, fmaf(mmf1, mmf1,
                    fmaf(10.0f * mmf2, mmf2, mmf3 * mmf3)));
        float rwa = A00 + A11 + 10.0f * A22 + A33;
        acc -= (double)fmaf(0.2f, rwa, rwm);

        // ---- cholesky of 5A -> sqrt5-scaled columns directly
        float i0 = __builtin_amdgcn_rsqf(A00);
        c00 = A00 * i0;
        c10 = A10 * i0; c20 = A20 * i0; c30 = A30 * i0;
        float b11 = fmaf(-c10, c10, A11);
        float i1 = __builtin_amdgcn_rsqf(b11);
        c11 = b11 * i1;
        c21 = fmaf(-c20, c10, A21) * i1;
        c31 = fmaf(-c30, c10, A31) * i1;
        float b22 = fmaf(-c21, c21, fmaf(-c20, c20, A22));
        float i2 = __builtin_amdgcn_rsqf(b22);
        c22 = b22 * i2;
        c32 = fmaf(-c31, c21, fmaf(-c30, c20, A32)) * i2;
        float b33 = fmaf(-c32, c32, fmaf(-c31, c31, fmaf(-c30, c30, A33)));
        c33 = b33 * __builtin_amdgcn_rsqf(b33);
    }

    if (l == 0) out[0] = (float)acc;
}

extern "C" void kernel_launch(void* const* d_in, const int* in_sizes, int n_in,
                              void* d_out, int out_size, void* d_ws, size_t ws_size,
                              hipStream_t stream) {
    (void)in_sizes; (void)n_in; (void)out_size; (void)d_ws; (void)ws_size;
    const float* p = (const float*)d_in[0];
    float* out = (float*)d_out;
    hipLaunchKernelGGL(horizon_kernel, dim3(1), dim3(64), 0, stream, p, out);
}

// Round 5
// 73.152 us; speedup vs baseline: 2.3467x; 1.0019x over previous
//
#include <hip/hip_runtime.h>
#include <math.h>

// HorizonReward: 60-step UT cartpole rollout, single wave, zero LDS.
// Structure: dynamics are AFFINE in the control u (thacc=g0+g1u, xacc=h0+h1u),
// so all reductions except the v1/v3 covariance terms run before u is known,
// overlapping the policy's exp2+DPP-reduce chain. f32 throughout except the
// angle accumulator rev (f64) — feedback-path errors stay ~1e-5, and R4
// empirically showed the trajectory amplification leaves absmax ~0.
//
// Row replication: roles keyed on (lane&15); all 4 rows hold identical data,
// so row r can reduce a DIFFERENT quantity (row-specialized packing): mean
// components in one rowsum, covariance products 3-4 per rowsum.

template <int CTRL>
__device__ __forceinline__ float dpp_add_f(float v) {
    int s = __builtin_amdgcn_update_dpp(0, __float_as_int(v), CTRL, 0xF, 0xF, true);
    return v + __int_as_float(s);
}
// sum within each 16-lane row: quad_perm[1,0,3,2], quad_perm[2,3,0,1],
// row_ror:4, row_ror:8
__device__ __forceinline__ float row_sum_f(float v) {
    v = dpp_add_f<0xB1>(v);
    v = dpp_add_f<0x4E>(v);
    v = dpp_add_f<0x124>(v);
    v = dpp_add_f<0x128>(v);
    return v;
}
__device__ __forceinline__ float rl(float v, int lane) {
    return __int_as_float(__builtin_amdgcn_readlane(__float_as_int(v), lane));
}
// full 64-lane sum -> lane63, via row_bcast15 / row_bcast31
__device__ __forceinline__ float wave_sum_f(float v) {
    v = row_sum_f(v);
    v = dpp_add_f<0x142>(v);
    v = dpp_add_f<0x143>(v);
    return rl(v, 63);
}

__global__ __launch_bounds__(64) void horizon_kernel(const float* __restrict__ p,
                                                     float* __restrict__ out) {
    const int l   = threadIdx.x;
    const int l15 = l & 15;
    const bool r1 = (l >> 4) & 1, r2 = (l >> 4) & 2;   // row bits

    const float SQL2E  = 1.2011224087864498f;   // sqrt(log2 e)
    const float INV_MT = 0.9090909090909091f;   // 1/1.1
    const float KCS    = -0.045454545454545456f;// -PML*LEN... = -0.05/1.1
    const double INV2PI_D = 0.15915494309189535;
    const float  INV2PI_F = 0.15915494309189535f;
    const float DIAG5  = 0.00251f;              // 5*(PN*DT + 2*JITTER)

    // per-lane RBF params, s pre-scaled so exp(-qn) = exp2(-(qn*log2e))
    float w = 0.0f, mu0 = 0.0f, mu1 = 0.0f, mu2 = 0.0f, mu3 = 0.0f;
    float s0=0,s1=0,s2=0,s3=0,s4=0,s5=0,s6=0,s7=0,s8=0,s9=0;
    if (l < 50) {
        w   = p[l];
        mu0 = p[ 50 + l]; mu1 = p[100 + l]; mu2 = p[150 + l]; mu3 = p[200 + l];
        const float* q = p + 250 + 10 * l;
        s0 = q[0]*SQL2E; s1 = q[1]*SQL2E; s2 = q[2]*SQL2E; s3 = q[3]*SQL2E;
        s4 = q[4]*SQL2E; s5 = q[5]*SQL2E; s6 = q[6]*SQL2E; s7 = q[7]*SQL2E;
        s8 = q[8]*SQL2E; s9 = q[9]*SQL2E;
    }

    // sigma-point role from (l&15)
    const float wlf  = (l15 == 0) ? 0.2f : ((l15 < 9) ? 0.1f : 0.0f);
    const float fw5  = 5.0f * wlf;
    const float osgn = (l15 >= 1 && l15 <= 4) ? 1.0f
                     : ((l15 >= 5 && l15 <= 8) ? -1.0f : 0.0f);
    const int   ocol = ((l15 >= 5 ? l15 - 5 : l15 - 1) & 3);

    // carried state (all f32 except angle accumulator rev)
    float mmf0 = 0.0f, mmf1 = 0.0f, mmf2 = 0.1f, mmf3 = 0.0f;
    float d0 = -mu0, d1 = -mu1, d2 = 0.1f - mu2, d3 = -mu3;
    double rev = 0.1 * INV2PI_D;                // theta / 2pi, kept in [0,1)
    float frmf = (float)rev;
    const float CI = 2.2360679774997896e-3f;    // sqrt5 * chol(JITTER*I)
    float c00=CI, c10=0.f, c20=0.f, c30=0.f;
    float c11=CI, c21=0.f, c31=0.f;
    float c22=CI, c32=0.f;
    float c33=CI;
    float acc = 0.0f;

    #pragma unroll 2
    for (int t = 0; t < 60; ++t) {
        // ================= pre-u phase =================
        // sigma offset for this lane (column ocol of sqrt5-scaled chol)
        float oo0 = osgn * ((ocol == 0) ? c00 : 0.0f);
        float oo1 = osgn * ((ocol == 0) ? c10 : ((ocol == 1) ? c11 : 0.0f));
        float oo2 = osgn * ((ocol == 0) ? c20 : ((ocol == 1) ? c21 :
                            ((ocol == 2) ? c22 : 0.0f)));
        float oo3 = osgn * ((ocol == 0) ? c30 : ((ocol == 1) ? c31 :
                            ((ocol == 2) ? c32 : c33)));

        float x1 = mmf1 + oo1;
        float x3 = mmf3 + oo3;

        // dynamics coefficients (affine in u): thacc=g0+g1u, xacc=h0+h1u
        float rv = __builtin_amdgcn_fractf(fmaf(oo2, INV2PI_F, frmf));
        float sn = __builtin_amdgcn_sinf(rv);
        float cs = __builtin_amdgcn_cosf(rv);
        float a   = (0.045454545454545456f * (x3 * x3)) * sn;  // temp - u/MT
        float den = fmaf(cs * cs, KCS, 0.6666666666666666f);
        float rden = __builtin_amdgcn_rcpf(den);
        float g0 = fmaf(9.8f, sn, -(cs * a)) * rden;
        float g1 = (-INV_MT) * (cs * rden);
        float kcs = KCS * cs;
        float h0 = fmaf(kcs, g0, a);
        float h1 = fmaf(kcs, g1, INV_MT);
        float al1 = fmaf(0.05f, h0, oo1), be1 = 0.05f * h1;   // dl1 = al1+be1*u
        float al3 = fmaf(0.05f, g0, oo3), be3 = 0.05f * g1;   // dl3 = al3+be3*u
        float dl0 = fmaf(0.05f, x1, oo0);                     // u-free
        float dl2 = fmaf(0.05f, x3, oo2);                     // u-free

        // mean sums, row-specialized: rows reduce {dl0, al1, dl2, al3}
        float selA = r1 ? (r2 ? al3 : al1) : (r2 ? dl2 : dl0);
        float PA = row_sum_f(wlf * selA);
        float A0 = rl(PA, 0), A1 = rl(PA, 16), A2 = rl(PA, 32), A3 = rl(PA, 48);
        // u-coefficient sums: rows {0, be1, 0, be3}
        float selB = r1 ? (r2 ? be3 : be1) : 0.0f;
        float PB = row_sum_f(wlf * selB);
        float B1 = rl(PB, 16), B3 = rl(PB, 48);

        // u-free covariance pieces: v0, v2 exact; v1 = va1+vb1*u etc.
        float v0 = dl0 - A0, v2 = dl2 - A2;
        float va1 = al1 - A1, vb1 = be1 - B1;
        float va3 = al3 - A3, vb3 = be3 - B3;
        // P1 rows: {A00=v0v0, A20=v2v0, A22=v2v2, 0}
        float sa = r1 ? v2 : v0;            // row0:v0 row1:v2 row2:v2(r2) ...
        sa = r2 ? (r1 ? 0.0f : v2) : sa;
        float sb = r2 ? v2 : v0;
        float P1 = row_sum_f((fw5 * sa) * sb);
        float A00 = rl(P1, 0) + DIAG5, A20 = rl(P1, 16), A22 = rl(P1, 32) + DIAG5;
        float i0 = __builtin_amdgcn_rsqf(A00);
        float nc00 = A00 * i0;
        float nc20 = A20 * i0;
        float b22p = fmaf(-nc20, nc20, A22);

        // mean components 0,2 update pre-u (no u dependence)
        float nmm0 = mmf0 + A0, nmm2 = mmf2 + A2;
        double revn = fma((double)A2, INV2PI_D, rev);
        rev = revn - floor(revn);
        float nfrm = (float)rev;

        // ================= policy (uses current d) =================
        float t0p = fmaf(s0, d0, s5 * d2);
        float t1p = s6 * d2;
        float t2p = s2 * d2;
        float t0v = fmaf(s4, d1, fmaf(s7, d3, t0p));
        float t1v = fmaf(s1, d1, fmaf(s8, d3, t1p));
        float t2v = fmaf(s9, d3, t2p);
        float t3v = s3 * d3;
        float qn = fmaf(t0v, t0v, fmaf(t1v, t1v, fmaf(t2v, t2v, t3v * t3v)));
        float val = wave_sum_f(w * __builtin_amdgcn_exp2f(-qn));
        float u = fminf(10.0f, fmaxf(-10.0f, val));

        // ================= post-u tail =================
        float rd1 = fmaf(B1, u, A1);
        float rd3 = fmaf(B3, u, A3);
        d0 += A0; d2 += A2; d1 += rd1; d3 += rd3;
        float nmm1 = mmf1 + rd1, nmm3 = mmf3 + rd3;

        float v1 = fmaf(vb1, u, va1);
        float v3 = fmaf(vb3, u, va3);
        // P2 rows: {A10=v1v0, A11=v1v1, A21=v1v2, A31=v1v3}
        float lo2 = r2 ? v2 : v0, hi2 = r2 ? v3 : v1;
        float P2 = row_sum_f((fw5 * v1) * (r1 ? hi2 : lo2));
        // P3 rows: {A30=v3v0, A32=v3v2, A33=v3v3, 0}
        float s3a = r1 ? v2 : v0;
        s3a = r2 ? (r1 ? 0.0f : v3) : s3a;
        float P3 = row_sum_f((fw5 * v3) * s3a);
        float A10 = rl(P2, 0), A11 = rl(P2, 16) + DIAG5;
        float A21 = rl(P2, 32), A31 = rl(P2, 48);
        float A30 = rl(P3, 0), A32 = rl(P3, 16), A33 = rl(P3, 32) + DIAG5;

        // reward (post-step mean & cov) — no feedback, f32 is plenty
        float rwm = fmaf(nmm0, nmm0, fmaf(nmm1, nmm1,
                    fmaf(10.0f * nmm2, nmm2, nmm3 * nmm3)));
        float rwa = A00 + A11 + 10.0f * A22 + A33;
        acc -= fmaf(0.2f, rwa, rwm);

        // remaining cholesky of 5*cov (column 0 partly done pre-u)
        float nc10 = A10 * i0;
        float nc30 = A30 * i0;
        float b11 = fmaf(-nc10, nc10, A11);
        float i1 = __builtin_amdgcn_rsqf(b11);
        float nc11 = b11 * i1;
        float nc21 = fmaf(-nc20, nc10, A21) * i1;
        float nc31 = fmaf(-nc30, nc10, A31) * i1;
        float b22 = fmaf(-nc21, nc21, b22p);
        float i2 = __builtin_amdgcn_rsqf(b22);
        float nc22 = b22 * i2;
        float nc32 = fmaf(-nc31, nc21, fmaf(-nc30, nc20, A32)) * i2;
        float b33 = fmaf(-nc32, nc32, fmaf(-nc31, nc31, fmaf(-nc30, nc30, A33)));
        float nc33 = b33 * __builtin_amdgcn_rsqf(b33);

        c00 = nc00; c10 = nc10; c20 = nc20; c30 = nc30;
        c11 = nc11; c21 = nc21; c31 = nc31;
        c22 = nc22; c32 = nc32; c33 = nc33;
        mmf0 = nmm0; mmf1 = nmm1; mmf2 = nmm2; mmf3 = nmm3;
        frmf = nfrm;
    }

    if (l == 0) out[0] = acc;
}

extern "C" void kernel_launch(void* const* d_in, const int* in_sizes, int n_in,
                              void* d_out, int out_size, void* d_ws, size_t ws_size,
                              hipStream_t stream) {
    (void)in_sizes; (void)n_in; (void)out_size; (void)d_ws; (void)ws_size;
    const float* p = (const float*)d_in[0];
    float* out = (float*)d_out;
    hipLaunchKernelGGL(horizon_kernel, dim3(1), dim3(64), 0, stream, p, out);
}